// Round 3
// baseline (487.707 us; speedup 1.0000x reference)
//
#include <hip/hip_runtime.h>
#include <math.h>

#define AA 48          // A = DIST^2 - 1
#define RR 25          // ROUNDS
#define TT 23          // R - 2 scan steps
#define ND 1176        // A*(A+1)/2
#define BPB 4          // batches per block
#define NT 320         // 5 waves; threads 0..293 own 4 outputs each
#define NOWN 294

// LDS layout (bytes)
#define LDS_XLS 0                       // 4800 B  : staged x bits
#define LDS_XXC 4800                    // 4416 B  : xx codes {2,3,4}
#define LDS_GT  9216                    // 42336 B : 9-float LUT rows [k][tid][9]
#define LDS_TOT (LDS_GT + 4 * NOWN * 9 * 4)   // 51552

// d_ws layout: float gt9[4*294*9] @0 (42336 B), uint32 pairs[1176] @42336
#define GT9_DWORDS (4 * NOWN * 9)       // 10584
#define GT9_BYTES  (GT9_DWORDS * 4)     // 42336

__global__ __launch_bounds__(256) void build_tables_kernel(
    const float* __restrict__ emb_diag,  // (1, 48)
    const float* __restrict__ emb_nd,    // (1, 1128, 4)
    float*    __restrict__ gt9,          // [4][294][9]
    uint32_t* __restrict__ pairs)        // [1176] i | (j<<8)
{
    int p = blockIdx.x * 256 + threadIdx.x;
    if (p >= ND) return;
    float v12 = 0.0f, v9 = 0.0f, v8 = 0.0f, v6 = 0.0f;
    int i, j;
    if (p < AA) {
        i = j = p;
        v9 = 1.0f / (1.0f + __expf(-emb_diag[p]));   // prod==9 -> sig_diag
    } else {
        int pp = p - AA;
        // row iy of strict upper triangle: S(iy) = 47*iy - iy*(iy-1)/2
        int iy = (int)((95.0f - sqrtf(9025.0f - 8.0f * (float)pp)) * 0.5f);
        if (iy < 0) iy = 0;
        if (iy > 46) iy = 46;
        while (iy < 46 && (47 * (iy + 1) - ((iy + 1) * iy) / 2) <= pp) ++iy;
        while (iy > 0 && (47 * iy - (iy * (iy - 1)) / 2) > pp) --iy;
        int S = 47 * iy - (iy * (iy - 1)) / 2;
        i = iy; j = iy + 1 + (pp - S);
        const float* e = emb_nd + pp * 4;
        v12 = 1.0f / (1.0f + __expf(-e[0]));
        v9  = v12 / (1.0f + __expf(-e[1]));
        v8  = v9  / (1.0f + __expf(-e[2]));
        v6  = v8  / (1.0f + __expf(-e[3]));
    }
    pairs[p] = (uint32_t)(i | (j << 8));
    // slot = 2*(ci+cj) + (ci&cj&1) - 8 : {4->0, 6->2, 8->4, 9->5, 12->6, 16->8}
    int tid = p >> 2, k = p & 3;
    float* row = gt9 + (k * NOWN + tid) * 9;
    row[0] = 0.0f;  // prod 4
    row[1] = 0.0f;
    row[2] = v6;    // prod 6
    row[3] = 0.0f;
    row[4] = v8;    // prod 8
    row[5] = v9;    // prod 9
    row[6] = v12;   // prod 12
    row[7] = 0.0f;
    row[8] = 1.0f;  // prod 16
}

__global__ __launch_bounds__(NT) void cnn_embed_kernel(
    const int*      __restrict__ x,      // (B, 25, 48) int32 in {0,1}
    const float*    __restrict__ gt9,    // [4][294][9] in d_ws
    const uint32_t* __restrict__ pairs,  // [1176] in d_ws
    float*          __restrict__ out,    // (B, 23, 1176)
    int B)
{
    __shared__ __align__(16) uint8_t smem[LDS_TOT];

    const int tid = threadIdx.x;
    const int b0  = blockIdx.x * BPB;

    // ---- Stage LUT rows: 42336 B = 2646 float4 ----
    {
        const float4* gsrc = (const float4*)gt9;
        float4* gdst = (float4*)(smem + LDS_GT);
        for (int g = tid; g < GT9_DWORDS / 4; g += NT) gdst[g] = gsrc[g];
    }

    // ---- Stage x bits as packed bytes ----
    {
        int validB = B - b0;
        if (validB > BPB) validB = BPB;
        const int validInts = validB * RR * AA;          // 1200/batch
        const int4* xg = (const int4*)(x + (size_t)b0 * RR * AA);
        for (int gg = tid; gg * 4 < validInts; gg += NT) {
            int4 v = xg[gg];
            uint32_t packed = (uint32_t)(v.x & 1) | ((uint32_t)(v.y & 1) << 8) |
                              ((uint32_t)(v.z & 1) << 16) | ((uint32_t)(v.w & 1) << 24);
            *((uint32_t*)&smem[LDS_XLS + gg * 4]) = packed;
        }
    }
    __syncthreads();

    // ---- Integer recurrence; thread = (bb, j), 192 active ----
    if (tid < BPB * AA) {
        const int bb = tid / AA;
        const int j  = tid - bb * AA;
        if (b0 + bb < B) {
            const uint8_t* xb  = smem + LDS_XLS + bb * RR * AA;
            uint8_t*       xxb = smem + LDS_XXC + bb * TT * AA;
            int st = -1, dt = 1;
            #pragma unroll
            for (int t = 0; t < TT; ++t) {
                int a  = xb[t * AA + j];
                int bv = xb[(t + 1) * AA + j];
                int c  = xb[(t + 2) * AA + j];
                int de = a ^ c;                       // data_err
                int me = de ? 0 : (a ^ bv);           // meas_err
                if (me) dt = -dt;
                st += dt * de;
                st = st < -1 ? -1 : (st > 1 ? 1 : st);
                if (!me) dt = (st == 0) ? dt : -st;   // dt*(1-st^2) - st
                xxb[t * AA + j] = (uint8_t)(st + 3);  // xx in {2,3,4}
            }
        }
    }
    __syncthreads();

    // ---- Output: thread owns p = 4*tid..4*tid+3; LUT lookup per output ----
    if (tid < NOWN) {
        uint4 pr = ((const uint4*)pairs)[tid];
        int ii[4], jj[4];
        ii[0] = pr.x & 0xFF; jj[0] = (pr.x >> 8) & 0xFF;
        ii[1] = pr.y & 0xFF; jj[1] = (pr.y >> 8) & 0xFF;
        ii[2] = pr.z & 0xFF; jj[2] = (pr.z >> 8) & 0xFF;
        ii[3] = pr.w & 0xFF; jj[3] = (pr.w >> 8) & 0xFF;
        // LUT row base (bytes), with the -8 slot bias (-32 B) folded in:
        // addr = rb[k] + (ci+cj)*8 + (ci&cj&1)*4
        uint32_t rb[4];
        #pragma unroll
        for (int k = 0; k < 4; ++k)
            rb[k] = (uint32_t)(LDS_GT + (k * NOWN + tid) * 36 - 32);

        #pragma unroll
        for (int bb = 0; bb < BPB; ++bb) {
            const int b = b0 + bb;
            if (b >= B) break;
            const uint8_t* xr0 = smem + LDS_XXC + bb * TT * AA;
            const uint8_t* pi[4], * pj[4];
            #pragma unroll
            for (int k = 0; k < 4; ++k) { pi[k] = xr0 + ii[k]; pj[k] = xr0 + jj[k]; }
            float* ob = out + (size_t)b * TT * ND + tid * 4;
            #pragma unroll
            for (int t = 0; t < TT; ++t) {
                float4 v;
                float* vf = (float*)&v;
                #pragma unroll
                for (int k = 0; k < 4; ++k) {
                    int ci = pi[k][t * AA];
                    int cj = pj[k][t * AA];
                    uint32_t off = rb[k] + (uint32_t)(ci + cj) * 8u +
                                   (uint32_t)(ci & cj & 1) * 4u;
                    vf[k] = *(const float*)&smem[off];
                }
                *((float4*)(ob + t * ND)) = v;
            }
        }
    }
}

extern "C" void kernel_launch(void* const* d_in, const int* in_sizes, int n_in,
                              void* d_out, int out_size, void* d_ws, size_t ws_size,
                              hipStream_t stream) {
    const int*   x  = (const int*)d_in[0];
    const float* ed = (const float*)d_in[1];
    const float* en = (const float*)d_in[2];
    float* out = (float*)d_out;
    float*    gt9   = (float*)d_ws;
    uint32_t* pairs = (uint32_t*)((char*)d_ws + GT9_BYTES);
    const int B = in_sizes[0] / (RR * AA);   // 4096

    hipLaunchKernelGGL(build_tables_kernel, dim3((ND + 255) / 256), dim3(256), 0, stream,
                       ed, en, gt9, pairs);
    const int grid = (B + BPB - 1) / BPB;
    hipLaunchKernelGGL(cnn_embed_kernel, dim3(grid), dim3(NT), 0, stream,
                       x, gt9, pairs, out, B);
}